// Round 7
// baseline (512.429 us; speedup 1.0000x reference)
//
#include <hip/hip_runtime.h>
#include <stdint.h>

#define NN 50000   // nodes
#define NE 600000  // edges
#define NG 1000    // graphs
#define AD 64      // input feat
#define HD 128     // hidden
#define OD 256     // output
#define BN_EPS_F 1e-5f
#define INV_N (1.0f / 50000.0f)
#define NB 196     // scan blocks = ceil(NN/256)

typedef __attribute__((ext_vector_type(8))) short  mbf16x8;
typedef __attribute__((ext_vector_type(4))) float  mf32x4;
typedef __attribute__((ext_vector_type(4))) unsigned short mu16x4;
typedef __attribute__((ext_vector_type(4))) unsigned int   mu32x4;

__device__ __forceinline__ float bf2f(unsigned short u) {
    union { unsigned int i; float f; } v; v.i = ((unsigned int)u) << 16; return v.f;
}
__device__ __forceinline__ unsigned short f2bf(float f) {
    union { float f; unsigned int i; } v; v.f = f;
    unsigned int r = v.i + 0x7fffu + ((v.i >> 16) & 1u);  // RNE
    return (unsigned short)(r >> 16);
}
// BN (scale, shift) for column c from raw sums
__device__ __forceinline__ void bn_ss(
    const float* __restrict__ stats, const float* __restrict__ gamma,
    const float* __restrict__ beta, int c, float& sc, float& sh)
{
    const float mean = stats[c] * INV_N;
    const float var = fmaxf(stats[128 + c] * INV_N - mean * mean, 0.f);
    const float inv = rsqrtf(var + BN_EPS_F);
    sc = gamma[c] * inv;
    sh = beta[c] - mean * sc;
}

// ---------------------------------------------------------------------------
// Weight pre-convert + transpose: wt[n][k] bf16 from W[k][n] fp32.
// layout: [emb 128x64][W1_0..2 128x128][W2_0..2 128x128]
// Also zeroes stats (first 1536 threads) and deg (first 50000 threads).
// ---------------------------------------------------------------------------
__global__ __launch_bounds__(256) void prew_kernel(
    const float* __restrict__ emb_W, const float* __restrict__ W1,
    const float* __restrict__ W2, unsigned short* __restrict__ wt,
    float* __restrict__ stats, int* __restrict__ deg)
{
    const int t = blockIdx.x * 256 + threadIdx.x;
    if (t < 1536) stats[t] = 0.f;
    if (t < NN) deg[t] = 0;
    if (t < 8192) {                    // emb: n=t>>6, k=t&63
        wt[t] = f2bf(emb_W[(t & 63) * 128 + (t >> 6)]);
    } else {
        const int t2 = t - 8192;
        if (t2 >= 6 * 16384) return;
        const int which = t2 >> 14, o = t2 & 16383;
        const int n = o >> 7, k = o & 127;
        const float* src = (which < 3) ? (W1 + (size_t)which * 16384)
                                       : (W2 + (size_t)(which - 3) * 16384);
        wt[t] = f2bf(src[k * 128 + n]);
    }
}

// ---------------------------------------------------------------------------
// GEMM: out_bf16[N,128] = A[N,K] @ Wt^T + bias
// AMODE: 0 = A fp32
//        2 = A bf16 with BN(stats_in)+ReLU on the fly
//        3 = A built by fused CSR gather: A[n] = (1+eps[l])*f(src[n]) +
//            sum_nbr f(src[nbr]); f = BN+ReLU(stats_in) if GBN else identity
// SOUT:  epilogue accumulates per-column sum/sumsq (fp32 acc) into stats_out
// ---------------------------------------------------------------------------
template <int K, int AMODE, bool SOUT, bool GBN>
__global__ __launch_bounds__(256) void gemm_kernel(
    const void* __restrict__ in, const unsigned short* __restrict__ Wt,
    const float* __restrict__ bias, const float* __restrict__ stats_in,
    const float* __restrict__ gamma, const float* __restrict__ beta,
    const int* __restrict__ rowptr, const int* __restrict__ adj,
    const float* __restrict__ eps, int l,
    unsigned short* __restrict__ out, float* __restrict__ stats_out, int n_rows)
{
    constexpr int SA = K + 8, SB = K + 8;
    __shared__ unsigned short zs[64 * SA];
    __shared__ unsigned short ws[128 * SB];
    __shared__ float ssl[128], ssh[128];
    __shared__ float lsum[128], lsq[128];

    const int tid = threadIdx.x;
    const int wave = tid >> 6, lane = tid & 63;
    const int row0 = blockIdx.x * 64;

    if (SOUT && tid < 128) { lsum[tid] = 0.f; lsq[tid] = 0.f; }
    if (AMODE == 2) {
        if (tid < 128) {
            float sc, sh; bn_ss(stats_in, gamma, beta, tid, sc, sh);
            ssl[tid] = sc; ssh[tid] = sh;
        }
        __syncthreads();
    }

    // ---- stage Wt (bf16 [n][k]) -> LDS, 16B vectors ----
    constexpr int NSH = (K == 128) ? 7 : 6;
    for (int i = tid; i < 128 * K / 8; i += 256) {
        const int base = i * 8;
        const int n = base >> NSH, k = base & (K - 1);
        *(mu32x4*)(&ws[n * SB + k]) = *(const mu32x4*)(Wt + base);
    }

    // ---- stage A tile -> LDS ----
    if constexpr (AMODE == 0) {
        const float* src = (const float*)in;
        constexpr int LPR = K / 4;
        for (int i = tid; i < 64 * LPR; i += 256) {
            const int r = i / LPR, c4 = (i % LPR) * 4;
            mf32x4 v = {0.f, 0.f, 0.f, 0.f};
            if (row0 + r < n_rows)
                v = *(const mf32x4*)(src + (size_t)(row0 + r) * K + c4);
            mu16x4 o;
            o[0] = f2bf(v[0]); o[1] = f2bf(v[1]); o[2] = f2bf(v[2]); o[3] = f2bf(v[3]);
            *(mu16x4*)(&zs[r * SA + c4]) = o;
        }
    } else if constexpr (AMODE == 2) {
        const unsigned short* src = (const unsigned short*)in;
        constexpr int LPR = K / 8;
        float sc[8], sh[8];
        {
            const int c8 = (tid % LPR) * 8;
#pragma unroll
            for (int j = 0; j < 8; j++) { sc[j] = ssl[c8 + j]; sh[j] = ssh[c8 + j]; }
        }
        for (int i = tid; i < 64 * LPR; i += 256) {
            const int r = i / LPR, c8 = (i % LPR) * 8;
            mu32x4 v = {0, 0, 0, 0};
            if (row0 + r < n_rows)
                v = *(const mu32x4*)(src + (size_t)(row0 + r) * K + c8);
            const unsigned short* u = (const unsigned short*)&v;
            mu16x4 oa, ob;
#pragma unroll
            for (int j = 0; j < 4; j++)
                oa[j] = f2bf(fmaxf(bf2f(u[j]) * sc[j] + sh[j], 0.f));
#pragma unroll
            for (int j = 0; j < 4; j++)
                ob[j] = f2bf(fmaxf(bf2f(u[4 + j]) * sc[4 + j] + sh[4 + j], 0.f));
            *(mu16x4*)(&zs[r * SA + c8]) = oa;
            *(mu16x4*)(&zs[r * SA + c8 + 4]) = ob;
        }
    } else {  // AMODE == 3: fused CSR gather staging (K==128)
        const unsigned short* src = (const unsigned short*)in;
        const int rowgrp = tid >> 4;          // 0..15
        const int c0 = (tid & 15) * 8;
        float sc[8], sh[8];
        if constexpr (GBN) {
#pragma unroll
            for (int j = 0; j < 8; j++) bn_ss(stats_in, gamma, beta, c0 + j, sc[j], sh[j]);
        }
        const float e1 = 1.0f + eps[l];
#pragma unroll
        for (int rr = 0; rr < 4; rr++) {
            const int r = rowgrp * 4 + rr;
            const int node = row0 + r;
            float acc[8];
            if (node < n_rows) {
                mu32x4 v = *(const mu32x4*)(src + (size_t)node * HD + c0);
                const unsigned short* u = (const unsigned short*)&v;
#pragma unroll
                for (int j = 0; j < 8; j++) {
                    float f = bf2f(u[j]);
                    if (GBN) f = fmaxf(f * sc[j] + sh[j], 0.f);
                    acc[j] = e1 * f;
                }
                const int s = rowptr[node], t1 = rowptr[node + 1];
                int i = s;
                for (; i + 4 <= t1; i += 4) {
                    const int n0 = adj[i], n1 = adj[i + 1];
                    const int n2 = adj[i + 2], n3 = adj[i + 3];
                    mu32x4 v0 = *(const mu32x4*)(src + (size_t)n0 * HD + c0);
                    mu32x4 v1 = *(const mu32x4*)(src + (size_t)n1 * HD + c0);
                    mu32x4 v2 = *(const mu32x4*)(src + (size_t)n2 * HD + c0);
                    mu32x4 v3 = *(const mu32x4*)(src + (size_t)n3 * HD + c0);
                    const unsigned short* u0 = (const unsigned short*)&v0;
                    const unsigned short* u1 = (const unsigned short*)&v1;
                    const unsigned short* u2 = (const unsigned short*)&v2;
                    const unsigned short* u3 = (const unsigned short*)&v3;
#pragma unroll
                    for (int j = 0; j < 8; j++) {
                        float f0 = bf2f(u0[j]), f1 = bf2f(u1[j]);
                        float f2 = bf2f(u2[j]), f3 = bf2f(u3[j]);
                        if (GBN) {
                            f0 = fmaxf(f0 * sc[j] + sh[j], 0.f);
                            f1 = fmaxf(f1 * sc[j] + sh[j], 0.f);
                            f2 = fmaxf(f2 * sc[j] + sh[j], 0.f);
                            f3 = fmaxf(f3 * sc[j] + sh[j], 0.f);
                        }
                        acc[j] += (f0 + f1) + (f2 + f3);
                    }
                }
                for (; i < t1; i++) {
                    mu32x4 v4 = *(const mu32x4*)(src + (size_t)adj[i] * HD + c0);
                    const unsigned short* u4 = (const unsigned short*)&v4;
#pragma unroll
                    for (int j = 0; j < 8; j++) {
                        float f = bf2f(u4[j]);
                        if (GBN) f = fmaxf(f * sc[j] + sh[j], 0.f);
                        acc[j] += f;
                    }
                }
            } else {
#pragma unroll
                for (int j = 0; j < 8; j++) acc[j] = 0.f;
            }
            mu16x4 o0, o1;
#pragma unroll
            for (int j = 0; j < 4; j++) o0[j] = f2bf(acc[j]);
#pragma unroll
            for (int j = 0; j < 4; j++) o1[j] = f2bf(acc[4 + j]);
            *(mu16x4*)(&zs[r * SA + c0]) = o0;
            *(mu16x4*)(&zs[r * SA + c0 + 4]) = o1;
        }
    }
    __syncthreads();

    // ---- MFMA ----
    mf32x4 acc[8];
#pragma unroll
    for (int t = 0; t < 8; t++) acc[t] = {0.f, 0.f, 0.f, 0.f};
    const int m = wave * 16 + (lane & 15);
    const int kq = (lane >> 4) * 8;
#pragma unroll
    for (int kk = 0; kk < K / 32; kk++) {
        const int k0 = kk * 32 + kq;
        mbf16x8 a = *(const mbf16x8*)(&zs[m * SA + k0]);
#pragma unroll
        for (int t = 0; t < 8; t++) {
            const int n = t * 16 + (lane & 15);
            mbf16x8 b = *(const mbf16x8*)(&ws[n * SB + k0]);
            acc[t] = __builtin_amdgcn_mfma_f32_16x16x32_bf16(a, b, acc[t], 0, 0, 0);
        }
    }

    // ---- epilogue: +bias, store bf16; fused column stats from fp32 acc ----
    const int rbase = wave * 16 + ((lane >> 4) << 2);
#pragma unroll
    for (int t = 0; t < 8; t++) {
        const int c = t * 16 + (lane & 15);
        const float bv = bias[c];
        float s = 0.f, q = 0.f;
#pragma unroll
        for (int r = 0; r < 4; r++) {
            const int grow = row0 + rbase + r;
            const float y = acc[t][r] + bv;
            if (grow < n_rows) {
                out[(size_t)grow * 128 + c] = f2bf(y);
                if (SOUT) { s += y; q += y * y; }
            }
        }
        if (SOUT) {
            s += __shfl_xor(s, 16); s += __shfl_xor(s, 32);
            q += __shfl_xor(q, 16); q += __shfl_xor(q, 32);
            if ((lane >> 4) == 0) {
                atomicAdd(&lsum[c], s);
                atomicAdd(&lsq[c], q);
            }
        }
    }
    if (SOUT) {
        __syncthreads();
        if (tid < 128) {
            atomicAdd(&stats_out[tid], lsum[tid]);
            atomicAdd(&stats_out[128 + tid], lsq[tid]);
        }
    }
}

// ---------------------------------------------------------------------------
// CSR build: histogram -> 3-phase parallel scan -> fill
// ---------------------------------------------------------------------------
__global__ __launch_bounds__(256) void deg_kernel(
    const int* __restrict__ ei, int* __restrict__ deg)
{
    const int e = blockIdx.x * 256 + threadIdx.x;
    if (e >= NE) return;
    const int row = ei[e];
    if ((unsigned)row < NN) atomicAdd(&deg[row], 1);
}

__global__ __launch_bounds__(256) void bscan_kernel(
    const int* __restrict__ deg, int* __restrict__ rowptr, int* __restrict__ bsum)
{
    __shared__ int sm[256];
    const int t = threadIdx.x, idx = blockIdx.x * 256 + t;
    const int d = (idx < NN) ? deg[idx] : 0;
    sm[t] = d; __syncthreads();
    for (int ofs = 1; ofs < 256; ofs <<= 1) {
        int v = (t >= ofs) ? sm[t - ofs] : 0;
        __syncthreads();
        sm[t] += v;
        __syncthreads();
    }
    if (idx < NN) rowptr[idx] = sm[t] - d;  // exclusive
    if (t == 255) bsum[blockIdx.x] = sm[255];
}

__global__ __launch_bounds__(256) void off_kernel(
    const int* __restrict__ bsum, int* __restrict__ boff, int* __restrict__ rowptr)
{
    __shared__ int sm[256];
    const int t = threadIdx.x;
    const int d = (t < NB) ? bsum[t] : 0;
    sm[t] = d; __syncthreads();
    for (int ofs = 1; ofs < 256; ofs <<= 1) {
        int v = (t >= ofs) ? sm[t - ofs] : 0;
        __syncthreads();
        sm[t] += v;
        __syncthreads();
    }
    if (t < NB) boff[t] = sm[t] - d;
    if (t == 255) rowptr[NN] = sm[255];
}

__global__ __launch_bounds__(256) void addoff_kernel(
    int* __restrict__ rowptr, const int* __restrict__ boff, int* __restrict__ cursor)
{
    const int idx = blockIdx.x * 256 + threadIdx.x;
    if (idx >= NN) return;
    const int v = rowptr[idx] + boff[idx >> 8];
    rowptr[idx] = v;
    cursor[idx] = v;
}

__global__ __launch_bounds__(256) void fill_kernel(
    const int* __restrict__ ei, int* __restrict__ cursor, int* __restrict__ adj)
{
    const int e = blockIdx.x * 256 + threadIdx.x;
    if (e >= NE) return;
    const int row = ei[e];
    const int col = ei[NE + e];
    if ((unsigned)row >= NN || (unsigned)col >= NN) return;
    adj[atomicAdd(&cursor[row], 1)] = col;
}

// graph start offsets from sorted batch_index
__global__ void starts_kernel(const int* __restrict__ batch, int* __restrict__ start)
{
    const int n = blockIdx.x * blockDim.x + threadIdx.x;
    if (n >= NN) return;
    int b = batch[n];
    int pb = (n == 0) ? -1 : batch[n - 1];
    if (b > NG - 1) b = NG - 1;
    if (pb > NG - 1) pb = NG - 1;
    for (int g = pb + 1; g <= b; g++) start[g] = n;
    if (n == NN - 1)
        for (int g = b + 1; g <= NG; g++) start[g] = NN;
}

// pooled[g] = sum over graph rows of BN+ReLU(y)   (final BN fused)
__global__ __launch_bounds__(256) void pool_kernel(
    const unsigned short* __restrict__ y, const int* __restrict__ start,
    const float* __restrict__ stats, const float* __restrict__ gamma,
    const float* __restrict__ beta, float* __restrict__ pooled)
{
    const int g = blockIdx.x;
    const int rg = threadIdx.x >> 4;          // row group 0..15
    const int c0 = (threadIdx.x & 15) * 8;
    float sc[8], sh[8];
#pragma unroll
    for (int j = 0; j < 8; j++) bn_ss(stats, gamma, beta, c0 + j, sc[j], sh[j]);
    int s = start[g], e = start[g + 1];
    if (s < 0) s = 0;
    if (e > NN) e = NN;
    float acc[8];
#pragma unroll
    for (int j = 0; j < 8; j++) acc[j] = 0.f;
    for (int n = s + rg; n < e; n += 16) {
        mu32x4 v = *(const mu32x4*)(y + (size_t)n * HD + c0);
        const unsigned short* u = (const unsigned short*)&v;
#pragma unroll
        for (int j = 0; j < 8; j++)
            acc[j] += fmaxf(bf2f(u[j]) * sc[j] + sh[j], 0.f);
    }
    __shared__ float red[16][128];
#pragma unroll
    for (int j = 0; j < 8; j++) red[rg][c0 + j] = acc[j];
    __syncthreads();
    if (threadIdx.x < 128) {
        float a = 0.f;
#pragma unroll
        for (int k = 0; k < 16; k++) a += red[k][threadIdx.x];
        pooled[(size_t)g * 128 + threadIdx.x] = a;
    }
}

// out[g][o] = pooled[g] . proj_W[:,o] + proj_b[o]   (fp32)
__global__ __launch_bounds__(256) void final_kernel(
    const float* __restrict__ pooled, const float* __restrict__ pw,
    const float* __restrict__ pb, float* __restrict__ out)
{
    __shared__ float pl[128];
    const int g = blockIdx.x, o = threadIdx.x;
    if (o < 128) pl[o] = pooled[(size_t)g * 128 + o];
    __syncthreads();
    float acc = pb[o];
#pragma unroll 4
    for (int k = 0; k < 128; k++) acc += pl[k] * pw[k * 256 + o];
    out[(size_t)g * 256 + o] = acc;
}

// ---------------------------------------------------------------------------
extern "C" void kernel_launch(void* const* d_in, const int* in_sizes, int n_in,
                              void* d_out, int out_size, void* d_ws, size_t ws_size,
                              hipStream_t stream)
{
    const float* x      = (const float*)d_in[0];
    const int*   edge   = (const int*)d_in[1];
    const int*   batch  = (const int*)d_in[2];
    const float* emb_W  = (const float*)d_in[4];
    const float* emb_b  = (const float*)d_in[5];
    const float* W1     = (const float*)d_in[6];
    const float* b1     = (const float*)d_in[7];
    const float* g1     = (const float*)d_in[8];
    const float* be1    = (const float*)d_in[9];
    const float* W2     = (const float*)d_in[10];
    const float* b2     = (const float*)d_in[11];
    const float* g2     = (const float*)d_in[12];
    const float* be2    = (const float*)d_in[13];
    const float* eps    = (const float*)d_in[14];
    const float* proj_W = (const float*)d_in[15];
    const float* proj_b = (const float*)d_in[16];
    float* out = (float*)d_out;

    char* ws = (char*)d_ws;
    size_t off = 0;
    auto take = [&](size_t bytes) -> char* {
        char* p = ws + off;
        off += (bytes + 255) & ~(size_t)255;
        return p;
    };
    float*          stats  = (float*)take(6 * 2 * HD * 4);
    int*            start  = (int*)take((NG + 1) * 4);
    int*            deg    = (int*)take(NN * 4);
    int*            rowptr = (int*)take((NN + 1) * 4);
    int*            cursor = (int*)take(NN * 4);
    int*            bsum   = (int*)take(256 * 4);
    int*            boff   = (int*)take(256 * 4);
    float*          pooled = (float*)take((size_t)NG * HD * 4);
    unsigned short* wt     = (unsigned short*)take((size_t)(8192 + 6 * 16384) * 2);
    int*            adj    = (int*)take((size_t)NE * 4);
    unsigned short* y1buf  = (unsigned short*)take((size_t)NN * HD * 2);
    unsigned short* y2buf  = (unsigned short*)take((size_t)NN * HD * 2);

    const int gemm_grid = (NN + 63) / 64;  // 782

    // weight pre-convert/transpose (+ zero stats/deg) + CSR build
    prew_kernel<<<(8192 + 6 * 16384 + 255) / 256, 256, 0, stream>>>(
        emb_W, W1, W2, wt, stats, deg);
    deg_kernel<<<(NE + 255) / 256, 256, 0, stream>>>(edge, deg);
    bscan_kernel<<<NB, 256, 0, stream>>>(deg, rowptr, bsum);
    off_kernel<<<1, 256, 0, stream>>>(bsum, boff, rowptr);
    addoff_kernel<<<NB, 256, 0, stream>>>(rowptr, boff, cursor);
    fill_kernel<<<(NE + 255) / 256, 256, 0, stream>>>(edge, cursor, adj);

    // embed: y2buf = x @ emb_W + emb_b
    gemm_kernel<AD, 0, false, false><<<gemm_grid, 256, 0, stream>>>(
        x, wt, emb_b, nullptr, nullptr, nullptr, nullptr, nullptr, nullptr, 0,
        y2buf, nullptr, NN);

    for (int l = 0; l < 3; l++) {
        // GEMM1 with fused CSR-gather staging
        if (l == 0)
            gemm_kernel<HD, 3, true, false><<<gemm_grid, 256, 0, stream>>>(
                y2buf, wt + 8192 + (size_t)l * 16384, b1 + l * HD,
                nullptr, nullptr, nullptr, rowptr, adj, eps, l,
                y1buf, stats + (2 * l) * 256, NN);
        else
            gemm_kernel<HD, 3, true, true><<<gemm_grid, 256, 0, stream>>>(
                y2buf, wt + 8192 + (size_t)l * 16384, b1 + l * HD,
                stats + (2 * l - 1) * 256, g2 + (l - 1) * HD, be2 + (l - 1) * HD,
                rowptr, adj, eps, l,
                y1buf, stats + (2 * l) * 256, NN);
        // GEMM2 with BN+ReLU-on-load of y1
        gemm_kernel<HD, 2, true, false><<<gemm_grid, 256, 0, stream>>>(
            y1buf, wt + 8192 + (size_t)(3 + l) * 16384, b2 + l * HD,
            stats + (2 * l) * 256, g1 + l * HD, be1 + l * HD,
            nullptr, nullptr, nullptr, 0,
            y2buf, stats + (2 * l + 1) * 256, NN);
    }

    starts_kernel<<<(NN + 255) / 256, 256, 0, stream>>>(batch, start);
    pool_kernel<<<NG, 256, 0, stream>>>(y2buf, start, stats + 5 * 256,
                                        g2 + 2 * HD, be2 + 2 * HD, pooled);
    final_kernel<<<NG, 256, 0, stream>>>(pooled, proj_W, proj_b, out);
}

// Round 8
// 472.615 us; speedup vs baseline: 1.0842x; 1.0842x over previous
//
#include <hip/hip_runtime.h>
#include <stdint.h>

#define NN 50000   // nodes
#define NE 600000  // edges
#define NG 1000    // graphs
#define AD 64      // input feat
#define HD 128     // hidden
#define OD 256     // output
#define BN_EPS_F 1e-5f
#define INV_N (1.0f / 50000.0f)
#define NB 196     // scan blocks = ceil(NN/256)
#define FILLB 586  // fill tail blocks (4 edges/thread)

typedef __attribute__((ext_vector_type(8))) short  mbf16x8;
typedef __attribute__((ext_vector_type(4))) float  mf32x4;
typedef __attribute__((ext_vector_type(4))) unsigned short mu16x4;
typedef __attribute__((ext_vector_type(4))) unsigned int   mu32x4;

__device__ __forceinline__ float bf2f(unsigned short u) {
    union { unsigned int i; float f; } v; v.i = ((unsigned int)u) << 16; return v.f;
}
__device__ __forceinline__ unsigned short f2bf(float f) {
    union { float f; unsigned int i; } v; v.f = f;
    unsigned int r = v.i + 0x7fffu + ((v.i >> 16) & 1u);  // RNE
    return (unsigned short)(r >> 16);
}
// BN (scale, shift) for column c from raw sums
__device__ __forceinline__ void bn_ss(
    const float* __restrict__ stats, const float* __restrict__ gamma,
    const float* __restrict__ beta, int c, float& sc, float& sh)
{
    const float mean = stats[c] * INV_N;
    const float var = fmaxf(stats[128 + c] * INV_N - mean * mean, 0.f);
    const float inv = rsqrtf(var + BN_EPS_F);
    sc = gamma[c] * inv;
    sh = beta[c] - mean * sc;
}

// ---------------------------------------------------------------------------
// Weight pre-convert + transpose: wt[n][k] bf16 from W[k][n] fp32.
// layout: [emb 128x64][W1_0..2 128x128][W2_0..2 128x128]
// Also zeroes stats (first 1536 threads) and deg (first 50000 threads).
// ---------------------------------------------------------------------------
__global__ __launch_bounds__(256) void prew_kernel(
    const float* __restrict__ emb_W, const float* __restrict__ W1,
    const float* __restrict__ W2, unsigned short* __restrict__ wt,
    float* __restrict__ stats, int* __restrict__ deg)
{
    const int t = blockIdx.x * 256 + threadIdx.x;
    if (t < 1536) stats[t] = 0.f;
    if (t < NN) deg[t] = 0;
    if (t < 8192) {                    // emb: n=t>>6, k=t&63
        wt[t] = f2bf(emb_W[(t & 63) * 128 + (t >> 6)]);
    } else {
        const int t2 = t - 8192;
        if (t2 >= 6 * 16384) return;
        const int which = t2 >> 14, o = t2 & 16383;
        const int n = o >> 7, k = o & 127;
        const float* src = (which < 3) ? (W1 + (size_t)which * 16384)
                                       : (W2 + (size_t)(which - 3) * 16384);
        wt[t] = f2bf(src[k * 128 + n]);
    }
}

// ---------------------------------------------------------------------------
// GEMM: out_bf16[N,128] = A[N,K] @ Wt^T + bias
// AMODE: 0 = A fp32, 1 = A bf16 plain, 2 = A bf16 with BN(stats_in)+ReLU
// SOUT:  epilogue accumulates per-column sum/sumsq (fp32 acc) into stats_out
// TAIL:  extra leading blocks doing independent work in the same launch:
//        1 = CSR fill (FILLB blocks, 4 edges/thread): t_a=edge, t_b=cursor, t_c=adj
//        2 = graph starts (NB blocks): t_a=batch, t_b=start
// ---------------------------------------------------------------------------
template <int K, int AMODE, bool SOUT, int TAIL>
__global__ __launch_bounds__(256) void gemm_kernel(
    const void* __restrict__ in, const unsigned short* __restrict__ Wt,
    const float* __restrict__ bias, const float* __restrict__ stats_in,
    const float* __restrict__ gamma, const float* __restrict__ beta,
    unsigned short* __restrict__ out, float* __restrict__ stats_out, int n_rows,
    const int* __restrict__ t_a, int* __restrict__ t_b, int* __restrict__ t_c)
{
    constexpr int TAILB = (TAIL == 1) ? FILLB : (TAIL == 2) ? NB : 0;
    if (TAIL != 0 && (int)blockIdx.x < TAILB) {
        const int t = blockIdx.x * 256 + threadIdx.x;
        if constexpr (TAIL == 1) {
            const int e0 = t * 4;
            if (e0 < NE) {   // NE % 4 == 0, so full int4 is in-bounds
                const int4 rv = *(const int4*)(t_a + e0);
                const int4 cv = *(const int4*)(t_a + NE + e0);
                if ((unsigned)rv.x < NN && (unsigned)cv.x < NN)
                    t_c[atomicAdd(&t_b[rv.x], 1)] = cv.x;
                if ((unsigned)rv.y < NN && (unsigned)cv.y < NN)
                    t_c[atomicAdd(&t_b[rv.y], 1)] = cv.y;
                if ((unsigned)rv.z < NN && (unsigned)cv.z < NN)
                    t_c[atomicAdd(&t_b[rv.z], 1)] = cv.z;
                if ((unsigned)rv.w < NN && (unsigned)cv.w < NN)
                    t_c[atomicAdd(&t_b[rv.w], 1)] = cv.w;
            }
        } else {  // TAIL == 2: graph start offsets from sorted batch_index
            if (t < NN) {
                int b = t_a[t];
                int pb = (t == 0) ? -1 : t_a[t - 1];
                if (b > NG - 1) b = NG - 1;
                if (pb > NG - 1) pb = NG - 1;
                for (int g = pb + 1; g <= b; g++) t_b[g] = t;
                if (t == NN - 1)
                    for (int g = b + 1; g <= NG; g++) t_b[g] = NN;
            }
        }
        return;
    }
    const int bid = blockIdx.x - TAILB;

    constexpr int SA = K + 8, SB = K + 8;
    __shared__ unsigned short zs[64 * SA];
    __shared__ unsigned short ws[128 * SB];
    __shared__ float ssl[128], ssh[128];
    __shared__ float lsum[128], lsq[128];

    const int tid = threadIdx.x;
    const int wave = tid >> 6, lane = tid & 63;
    const int row0 = bid * 64;

    if (SOUT && tid < 128) { lsum[tid] = 0.f; lsq[tid] = 0.f; }
    if (AMODE == 2) {
        if (tid < 128) {
            float sc, sh; bn_ss(stats_in, gamma, beta, tid, sc, sh);
            ssl[tid] = sc; ssh[tid] = sh;
        }
        __syncthreads();
    }

    // ---- stage Wt (bf16 [n][k]) -> LDS, 16B vectors ----
    constexpr int NSH = (K == 128) ? 7 : 6;
    for (int i = tid; i < 128 * K / 8; i += 256) {
        const int base = i * 8;
        const int n = base >> NSH, k = base & (K - 1);
        *(mu32x4*)(&ws[n * SB + k]) = *(const mu32x4*)(Wt + base);
    }

    // ---- stage A tile -> LDS ----
    if constexpr (AMODE == 0) {
        const float* src = (const float*)in;
        constexpr int LPR = K / 4;
        for (int i = tid; i < 64 * LPR; i += 256) {
            const int r = i / LPR, c4 = (i % LPR) * 4;
            mf32x4 v = {0.f, 0.f, 0.f, 0.f};
            if (row0 + r < n_rows)
                v = *(const mf32x4*)(src + (size_t)(row0 + r) * K + c4);
            mu16x4 o;
            o[0] = f2bf(v[0]); o[1] = f2bf(v[1]); o[2] = f2bf(v[2]); o[3] = f2bf(v[3]);
            *(mu16x4*)(&zs[r * SA + c4]) = o;
        }
    } else {
        const unsigned short* src = (const unsigned short*)in;
        constexpr int LPR = K / 8;
        float sc[8], sh[8];
        if constexpr (AMODE == 2) {
            const int c8 = (tid % LPR) * 8;   // fixed per thread (256 % LPR == 0)
#pragma unroll
            for (int j = 0; j < 8; j++) { sc[j] = ssl[c8 + j]; sh[j] = ssh[c8 + j]; }
        }
        for (int i = tid; i < 64 * LPR; i += 256) {
            const int r = i / LPR, c8 = (i % LPR) * 8;
            mu32x4 v = {0, 0, 0, 0};
            if (row0 + r < n_rows)
                v = *(const mu32x4*)(src + (size_t)(row0 + r) * K + c8);
            if constexpr (AMODE == 2) {
                const unsigned short* u = (const unsigned short*)&v;
                mu16x4 oa, ob;
#pragma unroll
                for (int j = 0; j < 4; j++)
                    oa[j] = f2bf(fmaxf(bf2f(u[j]) * sc[j] + sh[j], 0.f));
#pragma unroll
                for (int j = 0; j < 4; j++)
                    ob[j] = f2bf(fmaxf(bf2f(u[4 + j]) * sc[4 + j] + sh[4 + j], 0.f));
                *(mu16x4*)(&zs[r * SA + c8]) = oa;
                *(mu16x4*)(&zs[r * SA + c8 + 4]) = ob;
            } else {
                *(mu32x4*)(&zs[r * SA + c8]) = v;
            }
        }
    }
    __syncthreads();

    // ---- MFMA ----
    mf32x4 acc[8];
#pragma unroll
    for (int t = 0; t < 8; t++) acc[t] = {0.f, 0.f, 0.f, 0.f};
    const int m = wave * 16 + (lane & 15);
    const int kq = (lane >> 4) * 8;
#pragma unroll
    for (int kk = 0; kk < K / 32; kk++) {
        const int k0 = kk * 32 + kq;
        mbf16x8 a = *(const mbf16x8*)(&zs[m * SA + k0]);
#pragma unroll
        for (int t = 0; t < 8; t++) {
            const int n = t * 16 + (lane & 15);
            mbf16x8 b = *(const mbf16x8*)(&ws[n * SB + k0]);
            acc[t] = __builtin_amdgcn_mfma_f32_16x16x32_bf16(a, b, acc[t], 0, 0, 0);
        }
    }

    // ---- epilogue: +bias, store bf16; fused column stats from fp32 acc ----
    const int rbase = wave * 16 + ((lane >> 4) << 2);
#pragma unroll
    for (int t = 0; t < 8; t++) {
        const int c = t * 16 + (lane & 15);
        const float bv = bias[c];
        float s = 0.f, q = 0.f;
#pragma unroll
        for (int r = 0; r < 4; r++) {
            const int grow = row0 + rbase + r;
            const float y = acc[t][r] + bv;
            if (grow < n_rows) {
                out[(size_t)grow * 128 + c] = f2bf(y);
                if (SOUT) { s += y; q += y * y; }
            }
        }
        if (SOUT) {
            s += __shfl_xor(s, 16); s += __shfl_xor(s, 32);
            q += __shfl_xor(q, 16); q += __shfl_xor(q, 32);
            if ((lane >> 4) == 0) {
                atomicAdd(&lsum[c], s);
                atomicAdd(&lsq[c], q);
            }
        }
    }
    if (SOUT) {
        __syncthreads();
        if (tid < 128) {
            atomicAdd(&stats_out[tid], lsum[tid]);
            atomicAdd(&stats_out[128 + tid], lsq[tid]);
        }
    }
}

// ---------------------------------------------------------------------------
// CSR build: histogram (4 edges/thread) -> 3-phase parallel scan
// ---------------------------------------------------------------------------
__global__ __launch_bounds__(256) void deg_kernel(
    const int* __restrict__ ei, int* __restrict__ deg)
{
    const int e0 = (blockIdx.x * 256 + threadIdx.x) * 4;
    if (e0 >= NE) return;   // NE % 4 == 0 -> full int4 in-bounds
    const int4 rv = *(const int4*)(ei + e0);
    if ((unsigned)rv.x < NN) atomicAdd(&deg[rv.x], 1);
    if ((unsigned)rv.y < NN) atomicAdd(&deg[rv.y], 1);
    if ((unsigned)rv.z < NN) atomicAdd(&deg[rv.z], 1);
    if ((unsigned)rv.w < NN) atomicAdd(&deg[rv.w], 1);
}

__global__ __launch_bounds__(256) void bscan_kernel(
    const int* __restrict__ deg, int* __restrict__ rowptr, int* __restrict__ bsum)
{
    __shared__ int sm[256];
    const int t = threadIdx.x, idx = blockIdx.x * 256 + t;
    const int d = (idx < NN) ? deg[idx] : 0;
    sm[t] = d; __syncthreads();
    for (int ofs = 1; ofs < 256; ofs <<= 1) {
        int v = (t >= ofs) ? sm[t - ofs] : 0;
        __syncthreads();
        sm[t] += v;
        __syncthreads();
    }
    if (idx < NN) rowptr[idx] = sm[t] - d;  // exclusive
    if (t == 255) bsum[blockIdx.x] = sm[255];
}

__global__ __launch_bounds__(256) void off_kernel(
    const int* __restrict__ bsum, int* __restrict__ boff, int* __restrict__ rowptr)
{
    __shared__ int sm[256];
    const int t = threadIdx.x;
    const int d = (t < NB) ? bsum[t] : 0;
    sm[t] = d; __syncthreads();
    for (int ofs = 1; ofs < 256; ofs <<= 1) {
        int v = (t >= ofs) ? sm[t - ofs] : 0;
        __syncthreads();
        sm[t] += v;
        __syncthreads();
    }
    if (t < NB) boff[t] = sm[t] - d;
    if (t == 255) rowptr[NN] = sm[255];
}

__global__ __launch_bounds__(256) void addoff_kernel(
    int* __restrict__ rowptr, const int* __restrict__ boff, int* __restrict__ cursor)
{
    const int idx = blockIdx.x * 256 + threadIdx.x;
    if (idx >= NN) return;
    const int v = rowptr[idx] + boff[idx >> 8];
    rowptr[idx] = v;
    cursor[idx] = v;
}

// ---------------------------------------------------------------------------
// gather: z[n] = (1+eps[l])*f(src[n]) + sum_{c in adj[n]} f(src[c])
// f = BN+ReLU (from raw stats) when BN, else identity.
// 16 threads/node x 16B loads; 16 nodes per 256-thread block.
// ---------------------------------------------------------------------------
template <bool BN>
__global__ __launch_bounds__(256) void gather_kernel(
    const unsigned short* __restrict__ src, const int* __restrict__ rowptr,
    const int* __restrict__ adj, const float* __restrict__ stats,
    const float* __restrict__ gamma, const float* __restrict__ beta,
    const float* __restrict__ eps, int l, unsigned short* __restrict__ z)
{
    const int node = blockIdx.x * 16 + (threadIdx.x >> 4);
    const int c0 = (threadIdx.x & 15) * 8;
    if (node >= NN) return;
    float sc[8], sh[8];
    if (BN) {
#pragma unroll
        for (int j = 0; j < 8; j++) bn_ss(stats, gamma, beta, c0 + j, sc[j], sh[j]);
    }
    const float e = 1.0f + eps[l];
    float acc[8];
    {
        mu32x4 v = *(const mu32x4*)(src + (size_t)node * HD + c0);
        const unsigned short* u = (const unsigned short*)&v;
#pragma unroll
        for (int j = 0; j < 8; j++) {
            float f = bf2f(u[j]);
            if (BN) f = fmaxf(f * sc[j] + sh[j], 0.f);
            acc[j] = e * f;
        }
    }
    const int s = rowptr[node], t = rowptr[node + 1];
    int i = s;
    for (; i + 4 <= t; i += 4) {
        const int n0 = adj[i], n1 = adj[i + 1], n2 = adj[i + 2], n3 = adj[i + 3];
        mu32x4 v0 = *(const mu32x4*)(src + (size_t)n0 * HD + c0);
        mu32x4 v1 = *(const mu32x4*)(src + (size_t)n1 * HD + c0);
        mu32x4 v2 = *(const mu32x4*)(src + (size_t)n2 * HD + c0);
        mu32x4 v3 = *(const mu32x4*)(src + (size_t)n3 * HD + c0);
        const unsigned short* u0 = (const unsigned short*)&v0;
        const unsigned short* u1 = (const unsigned short*)&v1;
        const unsigned short* u2 = (const unsigned short*)&v2;
        const unsigned short* u3 = (const unsigned short*)&v3;
#pragma unroll
        for (int j = 0; j < 8; j++) {
            float f0 = bf2f(u0[j]), f1 = bf2f(u1[j]);
            float f2 = bf2f(u2[j]), f3 = bf2f(u3[j]);
            if (BN) {
                f0 = fmaxf(f0 * sc[j] + sh[j], 0.f);
                f1 = fmaxf(f1 * sc[j] + sh[j], 0.f);
                f2 = fmaxf(f2 * sc[j] + sh[j], 0.f);
                f3 = fmaxf(f3 * sc[j] + sh[j], 0.f);
            }
            acc[j] += (f0 + f1) + (f2 + f3);
        }
    }
    for (; i < t; i++) {
        mu32x4 v = *(const mu32x4*)(src + (size_t)adj[i] * HD + c0);
        const unsigned short* u = (const unsigned short*)&v;
#pragma unroll
        for (int j = 0; j < 8; j++) {
            float f = bf2f(u[j]);
            if (BN) f = fmaxf(f * sc[j] + sh[j], 0.f);
            acc[j] += f;
        }
    }
    mu16x4 o0, o1;
#pragma unroll
    for (int j = 0; j < 4; j++) o0[j] = f2bf(acc[j]);
#pragma unroll
    for (int j = 0; j < 4; j++) o1[j] = f2bf(acc[4 + j]);
    *(mu16x4*)(z + (size_t)node * HD + c0) = o0;
    *(mu16x4*)(z + (size_t)node * HD + c0 + 4) = o1;
}

// ---------------------------------------------------------------------------
// pooled[g] = sum over graph rows of BN+ReLU(y); then out[g] = pooled @ pw + pb
// 16 row-lanes x 16 feature-threads, LDS reduce, then 128x256 matvec.
// ---------------------------------------------------------------------------
__global__ __launch_bounds__(256) void poolfinal_kernel(
    const unsigned short* __restrict__ y, const int* __restrict__ start,
    const float* __restrict__ stats, const float* __restrict__ gamma,
    const float* __restrict__ beta, const float* __restrict__ pw,
    const float* __restrict__ pb, float* __restrict__ out)
{
    __shared__ float red[16][128];
    __shared__ float pl[128];
    const int g = blockIdx.x;
    const int rg = threadIdx.x >> 4;          // row group 0..15
    const int c0 = (threadIdx.x & 15) * 8;
    float sc[8], sh[8];
#pragma unroll
    for (int j = 0; j < 8; j++) bn_ss(stats, gamma, beta, c0 + j, sc[j], sh[j]);
    int s = start[g], e = start[g + 1];
    if (s < 0) s = 0;
    if (e > NN) e = NN;
    float acc[8];
#pragma unroll
    for (int j = 0; j < 8; j++) acc[j] = 0.f;
    for (int n = s + rg; n < e; n += 16) {
        mu32x4 v = *(const mu32x4*)(y + (size_t)n * HD + c0);
        const unsigned short* u = (const unsigned short*)&v;
#pragma unroll
        for (int j = 0; j < 8; j++)
            acc[j] += fmaxf(bf2f(u[j]) * sc[j] + sh[j], 0.f);
    }
#pragma unroll
    for (int j = 0; j < 8; j++) red[rg][c0 + j] = acc[j];
    __syncthreads();
    if (threadIdx.x < 128) {
        float a = 0.f;
#pragma unroll
        for (int k = 0; k < 16; k++) a += red[k][threadIdx.x];
        pl[threadIdx.x] = a;
    }
    __syncthreads();
    const int o = threadIdx.x;
    float facc = pb[o];
#pragma unroll 4
    for (int k = 0; k < 128; k++) facc += pl[k] * pw[k * 256 + o];
    out[(size_t)g * 256 + o] = facc;
}

// ---------------------------------------------------------------------------
extern "C" void kernel_launch(void* const* d_in, const int* in_sizes, int n_in,
                              void* d_out, int out_size, void* d_ws, size_t ws_size,
                              hipStream_t stream)
{
    const float* x      = (const float*)d_in[0];
    const int*   edge   = (const int*)d_in[1];
    const int*   batch  = (const int*)d_in[2];
    const float* emb_W  = (const float*)d_in[4];
    const float* emb_b  = (const float*)d_in[5];
    const float* W1     = (const float*)d_in[6];
    const float* b1     = (const float*)d_in[7];
    const float* g1     = (const float*)d_in[8];
    const float* be1    = (const float*)d_in[9];
    const float* W2     = (const float*)d_in[10];
    const float* b2     = (const float*)d_in[11];
    const float* g2     = (const float*)d_in[12];
    const float* be2    = (const float*)d_in[13];
    const float* eps    = (const float*)d_in[14];
    const float* proj_W = (const float*)d_in[15];
    const float* proj_b = (const float*)d_in[16];
    float* out = (float*)d_out;

    char* ws = (char*)d_ws;
    size_t off = 0;
    auto take = [&](size_t bytes) -> char* {
        char* p = ws + off;
        off += (bytes + 255) & ~(size_t)255;
        return p;
    };
    float*          stats  = (float*)take(6 * 2 * HD * 4);
    int*            start  = (int*)take((NG + 1) * 4);
    int*            deg    = (int*)take(NN * 4);
    int*            rowptr = (int*)take((NN + 1) * 4);
    int*            cursor = (int*)take(NN * 4);
    int*            bsum   = (int*)take(256 * 4);
    int*            boff   = (int*)take(256 * 4);
    unsigned short* wt     = (unsigned short*)take((size_t)(8192 + 6 * 16384) * 2);
    int*            adj    = (int*)take((size_t)NE * 4);
    unsigned short* zbuf   = (unsigned short*)take((size_t)NN * HD * 2);
    unsigned short* y1buf  = (unsigned short*)take((size_t)NN * HD * 2);
    unsigned short* y2buf  = (unsigned short*)take((size_t)NN * HD * 2);

    const int gemm_grid = (NN + 63) / 64;  // 782

    // weight pre-convert/transpose (+ zero stats/deg), then CSR build
    prew_kernel<<<(8192 + 6 * 16384 + 255) / 256, 256, 0, stream>>>(
        emb_W, W1, W2, wt, stats, deg);
    deg_kernel<<<FILLB, 256, 0, stream>>>(edge, deg);
    bscan_kernel<<<NB, 256, 0, stream>>>(deg, rowptr, bsum);
    off_kernel<<<1, 256, 0, stream>>>(bsum, boff, rowptr);
    addoff_kernel<<<NB, 256, 0, stream>>>(rowptr, boff, cursor);

    // packed launch: CSR fill (586 blocks) || embed GEMM (782 blocks)
    gemm_kernel<AD, 0, false, 1><<<FILLB + gemm_grid, 256, 0, stream>>>(
        x, wt, emb_b, nullptr, nullptr, nullptr, y2buf, nullptr, NN,
        edge, cursor, adj);

    for (int l = 0; l < 3; l++) {
        if (l == 0)
            gather_kernel<false><<<(NN + 15) / 16, 256, 0, stream>>>(
                y2buf, rowptr, adj, stats, g2, be2, eps, l, zbuf);
        else
            gather_kernel<true><<<(NN + 15) / 16, 256, 0, stream>>>(
                y2buf, rowptr, adj, stats + (2 * l - 1) * 256,
                g2 + (l - 1) * HD, be2 + (l - 1) * HD, eps, l, zbuf);
        gemm_kernel<HD, 1, true, 0><<<gemm_grid, 256, 0, stream>>>(
            zbuf, wt + 8192 + (size_t)l * 16384, b1 + l * HD,
            nullptr, nullptr, nullptr, y1buf, stats + (2 * l) * 256, NN,
            nullptr, nullptr, nullptr);
        if (l < 2)
            gemm_kernel<HD, 2, true, 0><<<gemm_grid, 256, 0, stream>>>(
                y1buf, wt + 8192 + (size_t)(3 + l) * 16384, b2 + l * HD,
                stats + (2 * l) * 256, g1 + l * HD, be1 + l * HD,
                y2buf, stats + (2 * l + 1) * 256, NN,
                nullptr, nullptr, nullptr);
        else
            // packed launch: graph starts (196 blocks) || last GEMM2 (782 blocks)
            gemm_kernel<HD, 2, true, 2><<<NB + gemm_grid, 256, 0, stream>>>(
                y1buf, wt + 8192 + (size_t)(3 + l) * 16384, b2 + l * HD,
                stats + (2 * l) * 256, g1 + l * HD, be1 + l * HD,
                y2buf, stats + (2 * l + 1) * 256, NN,
                batch, start, nullptr);
    }

    poolfinal_kernel<<<NG, 256, 0, stream>>>(
        y2buf, start, stats + 5 * 256, g2 + 2 * HD, be2 + 2 * HD,
        proj_W, proj_b, out);
}